// Round 1
// baseline (270.630 us; speedup 1.0000x reference)
//
#include <hip/hip_runtime.h>
#include <math.h>

// Chamfer distance, N=M=16384, D=3, fp32.
// R3 (fused): compute each pairwise dist^2 ONCE and feed BOTH reductions
// (row-min over j in registers, col-min over i via LDS combine).
// Per 2 unique pairs: 3 pk_fma + 1 pk_add + 4 v_min (~24 cy) vs the old
// two-pass 2*(3 pk_fma + 2 v_min) (~32 cy) => -25% VALU-FMA-pipe work.
// No atomics: partial-min arrays in ws; tiny sum kernel finishes.

typedef float v2f __attribute__((ext_vector_type(2)));

constexpr int N       = 16384;
constexpr int THREADS = 256;      // 32 (tr) x 8 (tc)
constexpr int ITILE   = 512;      // i's per block
constexpr int IT      = 16;       // i's per thread (ITILE/32)
constexpr int JSTEP   = 64;       // j's per step (8 tc * 8 j)
constexpr int CMSROW  = 132;      // cms row stride (128 + 4 pad -> 4-way banks, not 32)
constexpr int CMSJ    = 128;      // col-min LDS window (flush every 2 steps)
constexpr float INF_F = 3.402823466e+38f;

static __device__ __forceinline__ v2f vfma(v2f a, v2f b, v2f c) {
  return __builtin_elementwise_fma(a, b, c);
}
static __device__ __forceinline__ v2f vmin2(v2f a, v2f b) {
  return __builtin_elementwise_min(a, b);
}

// Each block: ITILE i's x jrange j's. dist^2 = (sa+sb) -2ax*bx -2ay*by -2az*bz
// via pk_fma chain seeded with sa+sb, so BOTH mins are over full dist^2 and
// the sum kernel needs no re-add of norms.
__global__ __launch_bounds__(THREADS, 3) void chamfer_tile(
    const float* __restrict__ p1, const float* __restrict__ p2,
    float* __restrict__ ws, int jrange, int JC) {
  __shared__ __align__(16) float smem[8320];
  float* cms = smem;          // [32][CMSROW] col-min staging
  float* a4  = smem + 4224;   // ax[512] ay az asq (SoA; aliased by rms later)
  float* lb  = smem + 6272;   // [4][512]: -2x, -2y, -2z, |b|^2 (SoA)
  float* rms = smem + 4224;   // [4][512] row-min staging, alias over a4

  float* rowPart = ws;                   // [JC][N]   min_j dist^2 partials
  float* colPart = ws + (size_t)JC * N;  // [32][N]   min_i dist^2 partials

  const int tid = threadIdx.x;
  const int tr  = tid & 31;
  const int tc  = tid >> 5;
  const int bid = blockIdx.x;
  const int ig  = bid & 31;   // consecutive blocks share the B tile (L2 reuse)
  const int jck = bid >> 5;
  const int i0  = ig * ITILE;
  const int j0  = jck * jrange;

  for (int t = tid; t < ITILE; t += THREADS) {
    const float* ap = p1 + (size_t)(i0 + t) * 3;
    const float x = ap[0], y = ap[1], z = ap[2];
    a4[t]        = x;
    a4[512 + t]  = y;
    a4[1024 + t] = z;
    a4[1536 + t] = fmaf(x, x, fmaf(y, y, z * z));
  }
  for (int t = tid; t < jrange; t += THREADS) {
    const float* bp = p2 + (size_t)(j0 + t) * 3;
    const float x = bp[0], y = bp[1], z = bp[2];
    lb[t]        = -2.0f * x;
    lb[512 + t]  = -2.0f * y;
    lb[1024 + t] = -2.0f * z;
    lb[1536 + t] = fmaf(x, x, fmaf(y, y, z * z));
  }
  __syncthreads();

  v2f rm[IT];
#pragma unroll
  for (int q = 0; q < IT; ++q) rm[q] = {INF_F, INF_F};

  const int nsteps = jrange / JSTEP;
  int cmscol = 0;
  for (int s = 0; s < nsteps; ++s) {
    // b fragment for this step: 8 j's per thread, packed as v2f pairs.
    // 64 lanes hit only 2 distinct LDS addresses -> broadcast, conflict-free.
    const int jb = s * JSTEP + tc * 8;
    v2f bx[4], by[4], bz[4], bw[4];
#pragma unroll
    for (int h = 0; h < 2; ++h) {
      const float4 t0 = *(const float4*)&lb[jb + 4 * h];
      const float4 t1 = *(const float4*)&lb[512 + jb + 4 * h];
      const float4 t2 = *(const float4*)&lb[1024 + jb + 4 * h];
      const float4 t3 = *(const float4*)&lb[1536 + jb + 4 * h];
      bx[2 * h] = {t0.x, t0.y}; bx[2 * h + 1] = {t0.z, t0.w};
      by[2 * h] = {t1.x, t1.y}; by[2 * h + 1] = {t1.z, t1.w};
      bz[2 * h] = {t2.x, t2.y}; bz[2 * h + 1] = {t2.z, t2.w};
      bw[2 * h] = {t3.x, t3.y}; bw[2 * h + 1] = {t3.z, t3.w};
    }
    v2f cm[4];
#pragma unroll
    for (int u = 0; u < 4; ++u) cm[u] = {INF_F, INF_F};

#pragma unroll
    for (int q = 0; q < IT; ++q) {
      // i index q*32+tr: 32 consecutive lanes read consecutive LDS words.
      const int il = q * 32 + tr;
      const float x = a4[il], y = a4[512 + il], z = a4[1024 + il];
      const float sa = a4[1536 + il];
      const v2f xx = {x, x}, yy = {y, y}, zz = {z, z}, ss = {sa, sa};
#pragma unroll
      for (int u = 0; u < 4; ++u) {
        const v2f d =
            vfma(xx, bx[u], vfma(yy, by[u], vfma(zz, bz[u], bw[u] + ss)));
        rm[q] = vmin2(rm[q], d);  // row-min (this thread's i's)
        cm[u] = vmin2(cm[u], d);  // col-min partial (this thread's i's only)
      }
    }

    // Stash this step's per-thread col-mins; combine across tr lazily.
    float* cp = &cms[tr * CMSROW + cmscol + tc * 8];
    *(float4*)(cp)     = make_float4(cm[0].x, cm[0].y, cm[1].x, cm[1].y);
    *(float4*)(cp + 4) = make_float4(cm[2].x, cm[2].y, cm[3].x, cm[3].y);
    cmscol += JSTEP;
    if (cmscol == CMSJ || s == nsteps - 1) {
      __syncthreads();
      if (tid < cmscol) {  // one thread per j column: min over 32 tr rows
        float m = cms[tid];
#pragma unroll 8
        for (int r = 1; r < 32; ++r) m = fminf(m, cms[r * CMSROW + tid]);
        const int jfb = (s + 1) * JSTEP - cmscol;
        colPart[(size_t)ig * N + j0 + jfb + tid] = m;
      }
      __syncthreads();
      cmscol = 0;
    }
  }

  // Row-min combine: horizontal v2f min, xor-32 merges the 2 tc's of each
  // wave, LDS pass merges the 4 waves. rms aliases a4 (dead after loop).
  __syncthreads();
  float h[IT];
#pragma unroll
  for (int q = 0; q < IT; ++q) {
    float v = fminf(rm[q].x, rm[q].y);
    v = fminf(v, __shfl_xor(v, 32, 64));
    h[q] = v;
  }
  const int w = tid >> 6;
  if ((tid & 32) == 0) {
#pragma unroll
    for (int q = 0; q < IT; ++q) rms[w * 512 + q * 32 + tr] = h[q];
  }
  __syncthreads();
  for (int t = tid; t < ITILE; t += THREADS) {
    const float m = fminf(fminf(rms[t], rms[512 + t]),
                          fminf(rms[1024 + t], rms[1536 + t]));
    rowPart[(size_t)jck * N + i0 + t] = m;
  }
}

// One thread per point (2*16384): min over partials (4 independent
// accumulators so L2 loads pipeline), sqrt, block-sum, one atomicAdd.
__global__ __launch_bounds__(THREADS) void chamfer_sum(
    const float* __restrict__ ws, float* __restrict__ out, int JC) {
  const int p = blockIdx.x * THREADS + threadIdx.x;  // 0..32767
  float m0 = INF_F, m1 = INF_F, m2 = INF_F, m3 = INF_F;
  if (p < N) {
    const float* rp = ws + p;
    for (int c = 0; c < JC; c += 4) {
      m0 = fminf(m0, rp[(size_t)(c + 0) * N]);
      m1 = fminf(m1, rp[(size_t)(c + 1) * N]);
      m2 = fminf(m2, rp[(size_t)(c + 2) * N]);
      m3 = fminf(m3, rp[(size_t)(c + 3) * N]);
    }
  } else {
    const float* cp = ws + (size_t)JC * N + (p - N);
#pragma unroll 4
    for (int g = 0; g < 32; ++g) m0 = fminf(m0, cp[(size_t)g * N]);
  }
  float d = sqrtf(fmaxf(fminf(fminf(m0, m1), fminf(m2, m3)), 0.0f));

  for (int off = 32; off > 0; off >>= 1) d += __shfl_down(d, off, 64);
  __shared__ float red[THREADS / 64];
  const int wave = threadIdx.x >> 6;
  const int lane = threadIdx.x & 63;
  if (lane == 0) red[wave] = d;
  __syncthreads();
  if (threadIdx.x == 0) {
    float s = 0.0f;
    for (int wv = 0; wv < THREADS / 64; ++wv) s += red[wv];
    atomicAdd(out, s);
  }
}

extern "C" void kernel_launch(void* const* d_in, const int* in_sizes, int n_in,
                              void* d_out, int out_size, void* d_ws, size_t ws_size,
                              hipStream_t stream) {
  const float* p1 = (const float*)d_in[0];
  const float* p2 = (const float*)d_in[1];
  float* out = (float*)d_out;
  float* ws = (float*)d_ws;

  // ws need: (JC + 32) * N floats. JC=64 -> 6 MB; degrade to JC=32 (4 MB,
  // proven available: baseline WRITE_SIZE was 4096 KB) if ws is tight.
  int JC = 64;
  while (JC > 32 && (size_t)(JC + 32) * N * sizeof(float) > ws_size) JC >>= 1;
  const int jrange = N / JC;

  hipMemsetAsync(out, 0, sizeof(float), stream);
  chamfer_tile<<<dim3(32 * JC), THREADS, 0, stream>>>(p1, p2, ws, jrange, JC);
  chamfer_sum<<<dim3((2 * N) / THREADS), THREADS, 0, stream>>>(ws, out, JC);
}

// Round 2
// 99.984 us; speedup vs baseline: 2.7067x; 2.7067x over previous
//
#include <hip/hip_runtime.h>
#include <math.h>

// Chamfer distance, N=M=16384, D=3, fp32.
// R4: fused single pass (each pair's d^2 computed ONCE, feeds row-min and
// col-min). R3's regression was scratch spill (SROA failure on v2f arrays:
// 940 MB of scratch traffic, VALUBusy 14%). R4 is spill-proof by
// construction: NO indexable per-thread arrays — all hot state is named
// v2f registers via macro-expanded bodies; a-splats come from an LDS table
// (ds_read_b64 of duplicated coords), so the inner loop is pure
// v_pk_fma/v_pk_min: 6 pk-instrs per 2 pairs (3/pair vs R2's ~6/pair).

typedef float v2f __attribute__((ext_vector_type(2)));

constexpr int N       = 16384;
constexpr int THREADS = 256;   // 32 (tr: i-dim) x 8 (tc: j-dim)
constexpr int ITILE   = 256;   // i's per block
constexpr int IG      = N / ITILE;  // 64 i-groups
constexpr int JSTEP   = 64;    // j's per step (8 tc * 8 j)
constexpr int SUPER   = 512;   // b-staging super-tile
constexpr int CMSW    = 260;   // cms row stride: 256 + 4 pad (float4 stores -> 4-way, not 32-way)
constexpr float INF_F = 3.402823466e+38f;

static __device__ __forceinline__ v2f vfma(v2f a, v2f b, v2f c) {
  return __builtin_elementwise_fma(a, b, c);
}
static __device__ __forceinline__ v2f vmin2(v2f a, v2f b) {
  return __builtin_elementwise_min(a, b);
}

// Block (ig, jck): i-tile [ig*256, +256) x j-chunk [jck*jrange, +jrange).
// d^2 = (sa+sb) - 2(ax bx + ay by + az bz), chain seeded with bw+ss so both
// mins are over the true d^2 (no post-add needed anywhere).
__global__ __launch_bounds__(THREADS) void chamfer_tile(
    const float* __restrict__ p1, const float* __restrict__ p2,
    float* __restrict__ rowPart, float* __restrict__ colPart,
    int jrange, int CC) {
  __shared__ float asx[4 * 512];     // a-splat table: comp c at c*512 + 2i (dup)
  __shared__ float bls[4 * SUPER];   // b SoA: -2x, -2y, -2z, |b|^2
  __shared__ float cms[32 * CMSW];   // col-min staging [32 tr][256 win + pad]

  const int tid = threadIdx.x;
  const int tr  = tid & 31;
  const int tc  = tid >> 5;
  const int bid = blockIdx.x;
  const int ig  = bid & (IG - 1);  // consecutive blocks share the b-chunk
  const int jck = bid >> 6;
  const int i0  = ig * ITILE;
  const int j0  = jck * jrange;

  {  // stage a-splats: one point per thread, each comp duplicated
    const float* ap = p1 + (size_t)(i0 + tid) * 3;
    const float x = ap[0], y = ap[1], z = ap[2];
    const int t2 = tid * 2;
    asx[t2] = x;           asx[t2 + 1] = x;
    asx[512 + t2] = y;     asx[512 + t2 + 1] = y;
    asx[1024 + t2] = z;    asx[1024 + t2 + 1] = z;
    const float sq = fmaf(x, x, fmaf(y, y, z * z));
    asx[1536 + t2] = sq;   asx[1536 + t2 + 1] = sq;
  }

  // Row-min state: 8 named v2f (i = q*32+tr, q=0..7), pk over 2 j's.
  v2f RM0 = {INF_F, INF_F}, RM1 = RM0, RM2 = RM0, RM3 = RM0;
  v2f RM4 = RM0, RM5 = RM0, RM6 = RM0, RM7 = RM0;

  for (int jt = 0; jt < jrange; jt += SUPER) {
    const int tile = (jrange - jt < SUPER) ? (jrange - jt) : SUPER;
    // stage b SoA (first iter: also publishes asx). Prior window's flush
    // barrier guarantees all reads of the old bls are done.
    for (int t = tid; t < tile; t += THREADS) {
      const float* bp = p2 + (size_t)(j0 + jt + t) * 3;
      const float x = bp[0], y = bp[1], z = bp[2];
      bls[t]        = -2.0f * x;
      bls[512 + t]  = -2.0f * y;
      bls[1024 + t] = -2.0f * z;
      bls[1536 + t] = fmaf(x, x, fmaf(y, y, z * z));
    }
    __syncthreads();

    const int nsteps = tile / JSTEP;  // 4 or 8, always multiple of 4
    for (int s = 0; s < nsteps; ++s) {
      const int jb = s * JSTEP + tc * 8;
      // b fragments for this thread's 8 j's: broadcast reads (addr uniform
      // over tr), register-pair aliasing only (no shuffle instrs).
      const float4 tx0 = *(const float4*)&bls[jb];
      const float4 tx1 = *(const float4*)&bls[jb + 4];
      const float4 ty0 = *(const float4*)&bls[512 + jb];
      const float4 ty1 = *(const float4*)&bls[512 + jb + 4];
      const float4 tz0 = *(const float4*)&bls[1024 + jb];
      const float4 tz1 = *(const float4*)&bls[1024 + jb + 4];
      const float4 tw0 = *(const float4*)&bls[1536 + jb];
      const float4 tw1 = *(const float4*)&bls[1536 + jb + 4];
      const v2f BX0 = {tx0.x, tx0.y}, BX1 = {tx0.z, tx0.w};
      const v2f BX2 = {tx1.x, tx1.y}, BX3 = {tx1.z, tx1.w};
      const v2f BY0 = {ty0.x, ty0.y}, BY1 = {ty0.z, ty0.w};
      const v2f BY2 = {ty1.x, ty1.y}, BY3 = {ty1.z, ty1.w};
      const v2f BZ0 = {tz0.x, tz0.y}, BZ1 = {tz0.z, tz0.w};
      const v2f BZ2 = {tz1.x, tz1.y}, BZ3 = {tz1.z, tz1.w};
      const v2f BW0 = {tw0.x, tw0.y}, BW1 = {tw0.z, tw0.w};
      const v2f BW2 = {tw1.x, tw1.y}, BW3 = {tw1.z, tw1.w};

      v2f CM0 = {INF_F, INF_F}, CM1 = CM0, CM2 = CM0, CM3 = CM0;

      // 8 i's x 8 j's per thread: 24 pk-instr per QBODY (3/pair).
#define QBODY(Q, RMQ)                                                        \
  {                                                                          \
    const int il = (Q)*64 + tr * 2;                                          \
    const v2f xx = *(const v2f*)&asx[il];                                    \
    const v2f yy = *(const v2f*)&asx[512 + il];                              \
    const v2f zz = *(const v2f*)&asx[1024 + il];                             \
    const v2f ss = *(const v2f*)&asx[1536 + il];                             \
    v2f d;                                                                   \
    d = vfma(xx, BX0, vfma(yy, BY0, vfma(zz, BZ0, BW0 + ss)));               \
    RMQ = vmin2(RMQ, d); CM0 = vmin2(CM0, d);                                \
    d = vfma(xx, BX1, vfma(yy, BY1, vfma(zz, BZ1, BW1 + ss)));               \
    RMQ = vmin2(RMQ, d); CM1 = vmin2(CM1, d);                                \
    d = vfma(xx, BX2, vfma(yy, BY2, vfma(zz, BZ2, BW2 + ss)));               \
    RMQ = vmin2(RMQ, d); CM2 = vmin2(CM2, d);                                \
    d = vfma(xx, BX3, vfma(yy, BY3, vfma(zz, BZ3, BW3 + ss)));               \
    RMQ = vmin2(RMQ, d); CM3 = vmin2(CM3, d);                                \
  }
      QBODY(0, RM0) QBODY(1, RM1) QBODY(2, RM2) QBODY(3, RM3)
      QBODY(4, RM4) QBODY(5, RM5) QBODY(6, RM6) QBODY(7, RM7)
#undef QBODY

      // stash this step's col-mins (exclusive slots, no barrier needed)
      float* cp = &cms[tr * CMSW + (s & 3) * JSTEP + tc * 8];
      *(float4*)(cp)     = make_float4(CM0.x, CM0.y, CM1.x, CM1.y);
      *(float4*)(cp + 4) = make_float4(CM2.x, CM2.y, CM3.x, CM3.y);

      if ((s & 3) == 3) {  // flush 256-j window: 1 thread per j over 32 rows
        __syncthreads();
        float m = cms[tid];
#pragma unroll
        for (int r = 1; r < 32; ++r) m = fminf(m, cms[r * CMSW + tid]);
        const int jg = j0 + jt + (s - 3) * JSTEP + tid;
        if (CC == IG) {
          colPart[(size_t)ig * N + jg] = m;
        } else {
          atomicMin((int*)colPart + (size_t)(ig & (CC - 1)) * N + jg,
                    __float_as_int(m));
        }
        __syncthreads();
      }
    }
  }

  // Row-min combine: horizontal, xor-32 merges the 2 tc's in each wave,
  // LDS pass (reusing cms) merges the 4 waves.
  float h0 = fminf(RM0.x, RM0.y), h1 = fminf(RM1.x, RM1.y);
  float h2 = fminf(RM2.x, RM2.y), h3 = fminf(RM3.x, RM3.y);
  float h4 = fminf(RM4.x, RM4.y), h5 = fminf(RM5.x, RM5.y);
  float h6 = fminf(RM6.x, RM6.y), h7 = fminf(RM7.x, RM7.y);
  h0 = fminf(h0, __shfl_xor(h0, 32, 64)); h1 = fminf(h1, __shfl_xor(h1, 32, 64));
  h2 = fminf(h2, __shfl_xor(h2, 32, 64)); h3 = fminf(h3, __shfl_xor(h3, 32, 64));
  h4 = fminf(h4, __shfl_xor(h4, 32, 64)); h5 = fminf(h5, __shfl_xor(h5, 32, 64));
  h6 = fminf(h6, __shfl_xor(h6, 32, 64)); h7 = fminf(h7, __shfl_xor(h7, 32, 64));
  const int w = tid >> 6;
  if ((tid & 32) == 0) {
    cms[w * 256 + 0 * 32 + tr] = h0;  cms[w * 256 + 1 * 32 + tr] = h1;
    cms[w * 256 + 2 * 32 + tr] = h2;  cms[w * 256 + 3 * 32 + tr] = h3;
    cms[w * 256 + 4 * 32 + tr] = h4;  cms[w * 256 + 5 * 32 + tr] = h5;
    cms[w * 256 + 6 * 32 + tr] = h6;  cms[w * 256 + 7 * 32 + tr] = h7;
  }
  __syncthreads();
  const float rmin = fminf(fminf(cms[tid], cms[256 + tid]),
                           fminf(cms[512 + tid], cms[768 + tid]));
  rowPart[(size_t)jck * N + i0 + tid] = rmin;
}

// One thread per point (2*16384): min over partial chunks (4 independent
// accumulators), sqrt, block-sum, one atomicAdd into out[0].
__global__ __launch_bounds__(THREADS) void chamfer_sum(
    const float* __restrict__ rowPart, const float* __restrict__ colPart,
    float* __restrict__ out, int JC, int CC) {
  const int p = blockIdx.x * THREADS + threadIdx.x;  // 0..32767
  float m0 = INF_F, m1 = INF_F, m2 = INF_F, m3 = INF_F;
  if (p < N) {
    const float* rp = rowPart + p;
    for (int c = 0; c < JC; c += 4) {
      m0 = fminf(m0, rp[(size_t)(c + 0) * N]);
      m1 = fminf(m1, rp[(size_t)(c + 1) * N]);
      m2 = fminf(m2, rp[(size_t)(c + 2) * N]);
      m3 = fminf(m3, rp[(size_t)(c + 3) * N]);
    }
  } else {
    const float* cp = colPart + (p - N);
    for (int c = 0; c < CC; c += 4) {
      m0 = fminf(m0, cp[(size_t)(c + 0) * N]);
      m1 = fminf(m1, cp[(size_t)(c + 1) * N]);
      m2 = fminf(m2, cp[(size_t)(c + 2) * N]);
      m3 = fminf(m3, cp[(size_t)(c + 3) * N]);
    }
  }
  float d = sqrtf(fmaxf(fminf(fminf(m0, m1), fminf(m2, m3)), 0.0f));

  for (int off = 32; off > 0; off >>= 1) d += __shfl_down(d, off, 64);
  __shared__ float red[THREADS / 64];
  const int wave = threadIdx.x >> 6;
  const int lane = threadIdx.x & 63;
  if (lane == 0) red[wave] = d;
  __syncthreads();
  if (threadIdx.x == 0) {
    float s = 0.0f;
    for (int wv = 0; wv < THREADS / 64; ++wv) s += red[wv];
    atomicAdd(out, s);
  }
}

extern "C" void kernel_launch(void* const* d_in, const int* in_sizes, int n_in,
                              void* d_out, int out_size, void* d_ws, size_t ws_size,
                              hipStream_t stream) {
  const float* p1 = (const float*)d_in[0];
  const float* p2 = (const float*)d_in[1];
  float* out = (float*)d_out;
  float* ws = (float*)d_ws;

  // ws: rowPart[JC][N] (plain, single-writer) + colPart[CC][N].
  // Preferred 64+64 = 8 MB; degrade JC, then share colPart rows via
  // int-bit atomicMin (d^2 >= 0 so float order == int order).
  const size_t F = ws_size / sizeof(float);
  int JC = 64, CC = 64;
  if ((size_t)(JC + CC) * N > F) JC = 32;             // 6 MB
  if ((size_t)(JC + CC) * N > F) CC = 32;             // 4 MB
  if ((size_t)(JC + CC) * N > F) { JC = 16; CC = 16; } // 2 MB
  if ((size_t)(JC + CC) * N > F) { JC = 8;  CC = 8; }  // 1 MB
  float* rowPart = ws;
  float* colPart = ws + (size_t)JC * N;

  hipMemsetAsync(out, 0, sizeof(float), stream);
  if (CC < IG) {  // atomicMin path needs +INF-ish init (0x7f7f7f7f = 3.39e38)
    hipMemsetAsync(colPart, 0x7f, (size_t)CC * N * sizeof(float), stream);
  }
  chamfer_tile<<<dim3(IG * JC), THREADS, 0, stream>>>(p1, p2, rowPart, colPart,
                                                      N / JC, CC);
  chamfer_sum<<<dim3((2 * N) / THREADS), THREADS, 0, stream>>>(rowPart, colPart,
                                                               out, JC, CC);
}

// Round 4
// 97.774 us; speedup vs baseline: 2.7679x; 1.0226x over previous
//
#include <hip/hip_runtime.h>
#include <math.h>

// Chamfer distance, N=M=16384, D=3, fp32.
// R6 = R5's kernel body + R4's plain launch structure.
// R5 failed because hipLaunchCooperativeKernel is not graph-capturable
// (output stayed 0.0 => absmax == ref magnitude). Body improvements kept:
//  - inline-asm v_pk_fma_f32/v_pk_add_f32 (R4 counters showed the
//    elementwise builtins scalarized: 12 VALU / 2 pairs; now 7 / 2 pairs)
//  - row-min via fminf(fminf(r,d.x),d.y) -> v_min3_f32
//  - col-min flush window 256 -> 128: LDS 48.5KB -> 30.2KB so 4 blocks/CU
//    (R4 ran 2 blocks/CU, VALUBusy 54% = issue-starved)
// Memset node dropped: tile's block 0 zeroes out[0]; kernel boundary orders
// it before chamfer_sum's atomicAdds.

typedef float v2f __attribute__((ext_vector_type(2)));

constexpr int N       = 16384;
constexpr int THREADS = 256;     // 32 (tr: i-dim) x 8 (tc: j-dim)
constexpr int ITILE   = 256;     // i's per block
constexpr int IG      = N / ITILE;  // 64
constexpr int JSTEP   = 64;      // j's per step (8 tc * 8 j)
constexpr int SUPER   = 256;     // b-staging tile
constexpr int NSTEP   = SUPER / JSTEP;  // 4 (even: every window flushed)
constexpr int CMSW    = 132;     // cms stride: 128 + 4 (16B-aligned pad)
constexpr int WIN     = 128;     // col-min flush window (2 steps)
constexpr float INF_F = 3.402823466e+38f;

static __device__ __forceinline__ v2f pk_fma(v2f a, v2f b, v2f c) {
  v2f d;
  asm("v_pk_fma_f32 %0, %1, %2, %3" : "=v"(d) : "v"(a), "v"(b), "v"(c));
  return d;
}
static __device__ __forceinline__ v2f pk_add(v2f a, v2f b) {
  v2f d;
  asm("v_pk_add_f32 %0, %1, %2" : "=v"(d) : "v"(a), "v"(b));
  return d;
}

// Block (ig, jck): i-tile [ig*256,+256) x j-chunk [jck*jrange,+jrange).
// d^2 = (sa+sb) - 2(ax bx + ay by + az bz); chain seeded with pk_add(bw,ss)
// so both row-min and col-min accumulate the true d^2 (no post-add anywhere).
__global__ __launch_bounds__(THREADS, 4) void chamfer_tile(
    const float* __restrict__ p1, const float* __restrict__ p2,
    float* __restrict__ rowPart, float* __restrict__ colPart,
    float* __restrict__ out, int jrange, int CC) {
  __shared__ __align__(16) float asx[2048];       // a-splats: comp c at c*512+2i (dup)
  __shared__ __align__(16) float bls[4 * SUPER];  // b SoA: -2x,-2y,-2z,|b|^2
  __shared__ __align__(16) float cms[32 * CMSW];  // col-min staging [32 tr][WIN]
  __shared__ __align__(16) float aux[2 * WIN];    // flush partials

  const int tid = threadIdx.x;
  const int tr  = tid & 31;
  const int tc  = tid >> 5;
  const int bid = blockIdx.x;
  const int ig  = bid & (IG - 1);  // consecutive blocks share the b-chunk
  const int jck = bid >> 6;
  const int i0  = ig * ITILE;
  const int j0  = jck * jrange;

  if (bid == 0 && tid == 0) *out = 0.0f;  // ordered before sum-kernel atomics

  {  // stage a-splats (one point per thread, coords duplicated for b64 read)
    const float* ap = p1 + (size_t)(i0 + tid) * 3;
    const float x = ap[0], y = ap[1], z = ap[2];
    const int t2 = tid * 2;
    asx[t2] = x;           asx[t2 + 1] = x;
    asx[512 + t2] = y;     asx[512 + t2 + 1] = y;
    asx[1024 + t2] = z;    asx[1024 + t2 + 1] = z;
    const float sq = fmaf(x, x, fmaf(y, y, z * z));
    asx[1536 + t2] = sq;   asx[1536 + t2 + 1] = sq;
  }

  // Row-min: scalar accumulator per owned i (i = q*32 + tr).
  float RM0 = INF_F, RM1 = INF_F, RM2 = INF_F, RM3 = INF_F;
  float RM4 = INF_F, RM5 = INF_F, RM6 = INF_F, RM7 = INF_F;

  for (int jt = 0; jt < jrange; jt += SUPER) {
    {  // stage b SoA (SUPER == THREADS: one store set per thread)
      const float* bp = p2 + (size_t)(j0 + jt + tid) * 3;
      const float x = bp[0], y = bp[1], z = bp[2];
      bls[tid]       = -2.0f * x;
      bls[256 + tid] = -2.0f * y;
      bls[512 + tid] = -2.0f * z;
      bls[768 + tid] = fmaf(x, x, fmaf(y, y, z * z));
    }
    __syncthreads();

    for (int s = 0; s < NSTEP; ++s) {
      const int jb = s * JSTEP + tc * 8;
      // b fragments: broadcast reads (uniform over tr), pair-aliased.
      const float4 tx0 = *(const float4*)&bls[jb];
      const float4 tx1 = *(const float4*)&bls[jb + 4];
      const float4 ty0 = *(const float4*)&bls[256 + jb];
      const float4 ty1 = *(const float4*)&bls[256 + jb + 4];
      const float4 tz0 = *(const float4*)&bls[512 + jb];
      const float4 tz1 = *(const float4*)&bls[512 + jb + 4];
      const float4 tw0 = *(const float4*)&bls[768 + jb];
      const float4 tw1 = *(const float4*)&bls[768 + jb + 4];
      const v2f BX0 = {tx0.x, tx0.y}, BX1 = {tx0.z, tx0.w};
      const v2f BX2 = {tx1.x, tx1.y}, BX3 = {tx1.z, tx1.w};
      const v2f BY0 = {ty0.x, ty0.y}, BY1 = {ty0.z, ty0.w};
      const v2f BY2 = {ty1.x, ty1.y}, BY3 = {ty1.z, ty1.w};
      const v2f BZ0 = {tz0.x, tz0.y}, BZ1 = {tz0.z, tz0.w};
      const v2f BZ2 = {tz1.x, tz1.y}, BZ3 = {tz1.z, tz1.w};
      const v2f BW0 = {tw0.x, tw0.y}, BW1 = {tw0.z, tw0.w};
      const v2f BW2 = {tw1.x, tw1.y}, BW3 = {tw1.z, tw1.w};

      v2f CM0 = {INF_F, INF_F}, CM1 = CM0, CM2 = CM0, CM3 = CM0;

      // 8 i x 8 j per thread; per 2 pairs: 1 pk_add + 3 pk_fma + min3 + 2 min.
#define QBODY(Q, RMQ)                                                       \
  {                                                                         \
    const int il = (Q)*64 + tr * 2;                                         \
    const v2f xx = *(const v2f*)&asx[il];                                   \
    const v2f yy = *(const v2f*)&asx[512 + il];                             \
    const v2f zz = *(const v2f*)&asx[1024 + il];                            \
    const v2f ss = *(const v2f*)&asx[1536 + il];                            \
    v2f d;                                                                  \
    d = pk_fma(xx, BX0, pk_fma(yy, BY0, pk_fma(zz, BZ0, pk_add(BW0, ss)))); \
    RMQ = fminf(fminf(RMQ, d.x), d.y);                                      \
    CM0.x = fminf(CM0.x, d.x); CM0.y = fminf(CM0.y, d.y);                   \
    d = pk_fma(xx, BX1, pk_fma(yy, BY1, pk_fma(zz, BZ1, pk_add(BW1, ss)))); \
    RMQ = fminf(fminf(RMQ, d.x), d.y);                                      \
    CM1.x = fminf(CM1.x, d.x); CM1.y = fminf(CM1.y, d.y);                   \
    d = pk_fma(xx, BX2, pk_fma(yy, BY2, pk_fma(zz, BZ2, pk_add(BW2, ss)))); \
    RMQ = fminf(fminf(RMQ, d.x), d.y);                                      \
    CM2.x = fminf(CM2.x, d.x); CM2.y = fminf(CM2.y, d.y);                   \
    d = pk_fma(xx, BX3, pk_fma(yy, BY3, pk_fma(zz, BZ3, pk_add(BW3, ss)))); \
    RMQ = fminf(fminf(RMQ, d.x), d.y);                                      \
    CM3.x = fminf(CM3.x, d.x); CM3.y = fminf(CM3.y, d.y);                   \
  }
      QBODY(0, RM0) QBODY(1, RM1) QBODY(2, RM2) QBODY(3, RM3)
      QBODY(4, RM4) QBODY(5, RM5) QBODY(6, RM6) QBODY(7, RM7)
#undef QBODY

      // stash col-mins (exclusive slots; 16B-aligned)
      float* cp = &cms[tr * CMSW + (s & 1) * JSTEP + tc * 8];
      *(float4*)(cp)     = make_float4(CM0.x, CM0.y, CM1.x, CM1.y);
      *(float4*)(cp + 4) = make_float4(CM2.x, CM2.y, CM3.x, CM3.y);

      if (s & 1) {  // flush 128-col window: 256 threads split 32 rows x 128 cols
        __syncthreads();
        const int col = tid & (WIN - 1);
        const int seg = tid >> 7;  // 0/1 -> rows [0,16) / [16,32)
        const float* rp = &cms[(seg * 16) * CMSW + col];
        float m = rp[0];
#pragma unroll
        for (int r = 1; r < 16; ++r) m = fminf(m, rp[r * CMSW]);
        aux[seg * WIN + col] = m;
        __syncthreads();
        if (tid < WIN) {
          const int jg = j0 + jt + (s - 1) * JSTEP + tid;
          const float mm = fminf(aux[tid], aux[WIN + tid]);
          if (CC == IG) {
            colPart[(size_t)ig * N + jg] = mm;
          } else {
            atomicMin((int*)colPart + (size_t)(ig & (CC - 1)) * N + jg,
                      __float_as_int(mm));
          }
        }
      }
    }
  }

  // Row-min combine: xor-32 merges the 2 tc's per wave; LDS merges 4 waves.
  float h0 = fminf(RM0, __shfl_xor(RM0, 32, 64));
  float h1 = fminf(RM1, __shfl_xor(RM1, 32, 64));
  float h2 = fminf(RM2, __shfl_xor(RM2, 32, 64));
  float h3 = fminf(RM3, __shfl_xor(RM3, 32, 64));
  float h4 = fminf(RM4, __shfl_xor(RM4, 32, 64));
  float h5 = fminf(RM5, __shfl_xor(RM5, 32, 64));
  float h6 = fminf(RM6, __shfl_xor(RM6, 32, 64));
  float h7 = fminf(RM7, __shfl_xor(RM7, 32, 64));
  const int w = tid >> 6;
  if ((tid & 32) == 0) {
    cms[w * 256 + 0 * 32 + tr] = h0;  cms[w * 256 + 1 * 32 + tr] = h1;
    cms[w * 256 + 2 * 32 + tr] = h2;  cms[w * 256 + 3 * 32 + tr] = h3;
    cms[w * 256 + 4 * 32 + tr] = h4;  cms[w * 256 + 5 * 32 + tr] = h5;
    cms[w * 256 + 6 * 32 + tr] = h6;  cms[w * 256 + 7 * 32 + tr] = h7;
  }
  __syncthreads();
  const float rmin = fminf(fminf(cms[tid], cms[256 + tid]),
                           fminf(cms[512 + tid], cms[768 + tid]));
  rowPart[(size_t)jck * N + i0 + tid] = rmin;
}

// One thread per point (2*16384): min over partial chunks (4 independent
// accumulators so loads pipeline), sqrt, block-sum, one atomicAdd into out.
__global__ __launch_bounds__(THREADS) void chamfer_sum(
    const float* __restrict__ rowPart, const float* __restrict__ colPart,
    float* __restrict__ out, int JC, int CC) {
  const int p = blockIdx.x * THREADS + threadIdx.x;  // 0..32767
  float m0 = INF_F, m1 = INF_F, m2 = INF_F, m3 = INF_F;
  if (p < N) {
    const float* rp = rowPart + p;
    for (int c = 0; c < JC; c += 4) {
      m0 = fminf(m0, rp[(size_t)(c + 0) * N]);
      m1 = fminf(m1, rp[(size_t)(c + 1) * N]);
      m2 = fminf(m2, rp[(size_t)(c + 2) * N]);
      m3 = fminf(m3, rp[(size_t)(c + 3) * N]);
    }
  } else {
    const float* cp = colPart + (p - N);
    for (int c = 0; c < CC; c += 4) {
      m0 = fminf(m0, cp[(size_t)(c + 0) * N]);
      m1 = fminf(m1, cp[(size_t)(c + 1) * N]);
      m2 = fminf(m2, cp[(size_t)(c + 2) * N]);
      m3 = fminf(m3, cp[(size_t)(c + 3) * N]);
    }
  }
  float d = sqrtf(fmaxf(fminf(fminf(m0, m1), fminf(m2, m3)), 0.0f));

  for (int off = 32; off > 0; off >>= 1) d += __shfl_down(d, off, 64);
  __shared__ float red[THREADS / 64];
  const int wave = threadIdx.x >> 6;
  const int lane = threadIdx.x & 63;
  if (lane == 0) red[wave] = d;
  __syncthreads();
  if (threadIdx.x == 0) {
    float s = 0.0f;
    for (int wv = 0; wv < THREADS / 64; ++wv) s += red[wv];
    atomicAdd(out, s);
  }
}

extern "C" void kernel_launch(void* const* d_in, const int* in_sizes, int n_in,
                              void* d_out, int out_size, void* d_ws, size_t ws_size,
                              hipStream_t stream) {
  const float* p1 = (const float*)d_in[0];
  const float* p2 = (const float*)d_in[1];
  float* out = (float*)d_out;
  float* ws = (float*)d_ws;

  // ws: rowPart[JC][N] + colPart[CC][N]; 64+64 = 8 MB (R4 proved ws >= 8MB).
  const size_t F = ws_size / sizeof(float);
  int JC = 64, CC = 64;
  if ((size_t)(JC + CC) * N > F) { JC = 32; CC = 32; }
  if ((size_t)(JC + CC) * N > F) { JC = 16; CC = 16; }
  if ((size_t)(JC + CC) * N > F) { JC = 8;  CC = 8;  }
  float* rowPart = ws;
  float* colPart = ws + (size_t)JC * N;

  if (CC < IG) {  // shared colPart rows -> atomicMin mode needs +INF init
    hipMemsetAsync(colPart, 0x7f, (size_t)CC * N * sizeof(float), stream);
  }
  chamfer_tile<<<dim3(IG * JC), THREADS, 0, stream>>>(p1, p2, rowPart, colPart,
                                                      out, N / JC, CC);
  chamfer_sum<<<dim3((2 * N) / THREADS), THREADS, 0, stream>>>(rowPart, colPart,
                                                               out, JC, CC);
}